// Round 2
// baseline (18013.765 us; speedup 1.0000x reference)
//
#include <hip/hip_runtime.h>
#include <stdint.h>
#include <math.h>

// Problem constants (B=2, T=2048, C=2048, NH=16, NG=4, HS=128)
#define Tn   2048
#define Cn   2048
#define BTn  4096          // B*T
#define NQKV 3072          // (16+2*4)*128
#define HID  8192

typedef unsigned short u16;
typedef float f32x4 __attribute__((ext_vector_type(4)));
typedef short s16x8 __attribute__((ext_vector_type(8)));   // 8 bf16 in 4 VGPRs

__device__ __forceinline__ float b2f(u16 u) { return __uint_as_float(((unsigned)u) << 16); }
__device__ __forceinline__ u16 f2b(float f) {
  unsigned i = __float_as_uint(f);
  return (u16)((i + 0x7fffu + ((i >> 16) & 1u)) >> 16);   // RNE
}

// async 16B global->LDS (lds dest must be wave-uniform base; HW scatters lane*16)
__device__ __forceinline__ void g2l16(const void* g, void* l) {
  __builtin_amdgcn_global_load_lds((const __attribute__((address_space(1))) unsigned int*)g,
                                   (__attribute__((address_space(3))) unsigned int*)l,
                                   16, 0, 0);
}

// ------- tiled transpose + fp32->bf16 cast: out[c][r] = bf16(in[r][c]) -------
__global__ __launch_bounds__(256) void transpose_f2b(const float* __restrict__ in,
                                                     u16* __restrict__ out, int R, int C) {
  __shared__ float tile[32][33];
  int bx = blockIdx.x * 32, by = blockIdx.y * 32;
  int tx = threadIdx.x, ty = threadIdx.y;  // (32,8)
  #pragma unroll
  for (int j = 0; j < 32; j += 8)
    tile[ty + j][tx] = in[(size_t)(by + ty + j) * C + bx + tx];
  __syncthreads();
  #pragma unroll
  for (int j = 0; j < 32; j += 8)
    out[(size_t)(bx + ty + j) * R + by + tx] = f2b(tile[tx][ty + j]);
}

// ---------------- layernorm: fp32 in, bf16 out ----------------
__global__ __launch_bounds__(256)
void layernorm_k(const float* __restrict__ x, const float* __restrict__ w,
                 const float* __restrict__ bb, u16* __restrict__ out) {
  __shared__ float red[256];
  __shared__ float sm, sv;
  const int tid = threadIdx.x;
  const long row = blockIdx.x;
  const float* xr = x + row * (long)Cn;
  float v[8];
  float s = 0.f;
  #pragma unroll
  for (int i = 0; i < 8; ++i) { v[i] = xr[i * 256 + tid]; s += v[i]; }
  red[tid] = s; __syncthreads();
  for (int st = 128; st > 0; st >>= 1) { if (tid < st) red[tid] += red[tid + st]; __syncthreads(); }
  if (tid == 0) sm = red[0] * (1.f / Cn);
  __syncthreads();
  const float mean = sm;
  float s2 = 0.f;
  #pragma unroll
  for (int i = 0; i < 8; ++i) { float d = v[i] - mean; s2 += d * d; }
  red[tid] = s2; __syncthreads();
  for (int st = 128; st > 0; st >>= 1) { if (tid < st) red[tid] += red[tid + st]; __syncthreads(); }
  if (tid == 0) sv = rsqrtf(red[0] * (1.f / Cn) + 1e-5f);
  __syncthreads();
  const float rstd = sv;
  #pragma unroll
  for (int i = 0; i < 8; ++i) {
    int c = i * 256 + tid;
    out[row * (long)Cn + c] = f2b((v[i] - mean) * rstd * w[c] + bb[c]);
  }
}

// ---- RoPE + split qkv(bf16) -> q[b,h,t,d], k[b,g,t,d], v[b,g,t,d] (bf16) ----
__global__ __launch_bounds__(256)
void rope_split(const u16* __restrict__ qkv, const float* __restrict__ cs,
                const float* __restrict__ sn, u16* __restrict__ q,
                u16* __restrict__ k, u16* __restrict__ v) {
  const long idx = (long)blockIdx.x * 256 + threadIdx.x;
  const int row = (int)(idx / NQKV);       // b*T + t
  const int col = (int)(idx % NQKV);
  const int b = row >> 11, t = row & 2047;
  const int g = col / 768, rr = col % 768, s = rr >> 7, d = rr & 127;
  const u16 raw = qkv[idx];
  if (s == 5) { v[((long)(b * 4 + g) * Tn + t) * 128 + d] = raw; return; }
  const float xv = b2f(raw);
  const float x2 = b2f(qkv[idx - d + (d ^ 64)]);
  const float c = cs[t * 128 + d];
  const float si = sn[t * 128 + d];
  const float rot = (d < 64) ? -x2 : x2;
  const float o = xv * c + rot * si;
  if (s == 4) k[((long)(b * 4 + g) * Tn + t) * 128 + d] = f2b(o);
  else        q[((long)(b * 16 + g * 4 + s) * Tn + t) * 128 + d] = f2b(o);
}

// -------- causal GQA attention: one block per (query row, head), bf16 I/O --------
__global__ __launch_bounds__(256)
void attn_k(const u16* __restrict__ q, const u16* __restrict__ k,
            const u16* __restrict__ v, u16* __restrict__ y) {
  __shared__ float sc[Tn];
  __shared__ float qs[128];
  __shared__ float red[256];
  const int t = blockIdx.x, bh = blockIdx.y;
  const int b = bh >> 4, h = bh & 15, g = h >> 2;
  const int tid = threadIdx.x;
  const u16* qrow = q + ((long)bh * Tn + t) * 128;
  const u16* kb = k + (long)(b * 4 + g) * Tn * 128;
  const u16* vb = v + (long)(b * 4 + g) * Tn * 128;
  if (tid < 128) qs[tid] = b2f(qrow[tid]) * 0.08838834764831845f;  // 1/sqrt(128)
  __syncthreads();
  const int nk = t + 1;
  for (int j = tid; j < nk; j += 256) {
    const ushort4* kr = (const ushort4*)(kb + (long)j * 128);
    float dot = 0.f;
    #pragma unroll
    for (int c = 0; c < 32; ++c) {
      ushort4 u = kr[c];
      dot += qs[4 * c] * b2f(u.x) + qs[4 * c + 1] * b2f(u.y) +
             qs[4 * c + 2] * b2f(u.z) + qs[4 * c + 3] * b2f(u.w);
    }
    sc[j] = dot;
  }
  __syncthreads();
  float lm = -1e30f;
  for (int j = tid; j < nk; j += 256) lm = fmaxf(lm, sc[j]);
  red[tid] = lm; __syncthreads();
  for (int st = 128; st > 0; st >>= 1) { if (tid < st) red[tid] = fmaxf(red[tid], red[tid + st]); __syncthreads(); }
  const float m = red[0];
  __syncthreads();
  float ls = 0.f;
  for (int j = tid; j < nk; j += 256) { float p = __expf(sc[j] - m); sc[j] = p; ls += p; }
  red[tid] = ls; __syncthreads();
  for (int st = 128; st > 0; st >>= 1) { if (tid < st) red[tid] += red[tid + st]; __syncthreads(); }
  const float linv = 1.f / red[0];
  __syncthreads();
  const int d = tid & 127, half = tid >> 7;
  float o = 0.f;
  for (int j = half; j < nk; j += 2) o += sc[j] * b2f(vb[(long)j * 128 + d]);  // coalesced across lanes
  red[tid] = o; __syncthreads();
  if (tid < 128)
    y[((long)(b * Tn + t)) * Cn + h * 128 + d] = f2b((red[tid] + red[tid + 128]) * linv);
}

// ---------------- m97-style MFMA GEMM: C = A[MxK] * Bt[NxK]^T, fused epilogues ----------------
// EPI 0: ob (bf16)  = acc
// EPI 1: of (fp32)  = acc + res (fp32)     [residual add]
// EPI 2: ob (bf16)  = gelu_exact(acc)
template <int EPI>
__global__ __launch_bounds__(256, 2)
void gemm_bt(const u16* __restrict__ A, const u16* __restrict__ Bt,
             const float* __restrict__ res, u16* __restrict__ ob,
             float* __restrict__ of, int M, int N, int K) {
  __shared__ __align__(16) u16 As[128 * 32];
  __shared__ __align__(16) u16 Bs[128 * 32];
  const int tid = threadIdx.x;
  const int wave = tid >> 6, lane = tid & 63;
  const int wy = wave >> 1, wx = wave & 1;
  const long m0 = (long)blockIdx.y * 128, n0 = (long)blockIdx.x * 128;
  const int lr = lane >> 2;          // 0..15: row within 16-row segment
  const int lc = (lane & 3) << 3;    // 0,8,16,24: k-offset (u16 units)
  const int fr = lane & 15, quad = lane >> 4;
  f32x4 acc[4][4] = {};

  for (int k0 = 0; k0 < K; k0 += 32) {
    __syncthreads();
    #pragma unroll
    for (int i = 0; i < 2; ++i) {
      const int seg = wave * 2 + i;          // 0..7, wave-uniform
      const int row = seg * 16 + lr;         // 0..127
      g2l16(A + (m0 + row) * (long)K + k0 + lc, As + seg * 512);
      g2l16(Bt + (n0 + row) * (long)K + k0 + lc, Bs + seg * 512);
    }
    __syncthreads();   // compiler emits vmcnt(0) drain before barrier
    s16x8 af[4], bfr[4];
    #pragma unroll
    for (int mi = 0; mi < 4; ++mi)
      af[mi] = *(const s16x8*)(As + (wy * 64 + mi * 16 + fr) * 32 + quad * 8);
    #pragma unroll
    for (int ni = 0; ni < 4; ++ni)
      bfr[ni] = *(const s16x8*)(Bs + (wx * 64 + ni * 16 + fr) * 32 + quad * 8);
    #pragma unroll
    for (int mi = 0; mi < 4; ++mi)
      #pragma unroll
      for (int ni = 0; ni < 4; ++ni)
        acc[mi][ni] = __builtin_amdgcn_mfma_f32_16x16x32_bf16(af[mi], bfr[ni], acc[mi][ni], 0, 0, 0);
  }

  #pragma unroll
  for (int mi = 0; mi < 4; ++mi)
    #pragma unroll
    for (int ni = 0; ni < 4; ++ni)
      #pragma unroll
      for (int r = 0; r < 4; ++r) {
        const long row = m0 + wy * 64 + mi * 16 + quad * 4 + r;
        const long col = n0 + wx * 64 + ni * 16 + fr;
        const long idx = row * N + col;
        const float vv = acc[mi][ni][r];
        if (EPI == 0) ob[idx] = f2b(vv);
        else if (EPI == 1) of[idx] = vv + res[idx];
        else ob[idx] = f2b(0.5f * vv * (1.0f + erff(vv * 0.70710678118654752f)));
      }
}

extern "C" void kernel_launch(void* const* d_in, const int* in_sizes, int n_in,
                              void* d_out, int out_size, void* d_ws, size_t ws_size,
                              hipStream_t stream) {
  (void)in_sizes; (void)n_in; (void)out_size; (void)ws_size;
  const float* x      = (const float*)d_in[0];
  const float* cosb   = (const float*)d_in[1];
  const float* sinb   = (const float*)d_in[2];
  const float* ln1w   = (const float*)d_in[3];
  const float* ln1b   = (const float*)d_in[4];
  const float* ln2w   = (const float*)d_in[5];
  const float* ln2b   = (const float*)d_in[6];
  const float* w_attn = (const float*)d_in[7];
  const float* w_proj = (const float*)d_in[8];
  const float* w_fc   = (const float*)d_in[9];
  const float* w_mp   = (const float*)d_in[10];
  float* out = (float*)d_out;

  char* p = (char*)d_ws;
  auto alloc = [&](size_t bytes) { char* r = p; p += (bytes + 255) & ~(size_t)255; return (void*)r; };
  u16*  wT_attn = (u16*)alloc((size_t)NQKV * Cn * 2);   // bf16 [3072][2048]
  u16*  wT_proj = (u16*)alloc((size_t)Cn * Cn * 2);     // bf16 [2048][2048]
  u16*  wT_fc   = (u16*)alloc((size_t)HID * Cn * 2);    // bf16 [8192][2048]
  u16*  wT_mp   = (u16*)alloc((size_t)Cn * HID * 2);    // bf16 [2048][8192]
  u16*  n12     = (u16*)alloc((size_t)BTn * Cn * 2);    // n1, then n2 (bf16)
  u16*  qkv     = (u16*)alloc((size_t)BTn * NQKV * 2);  // qkv, then y (bf16)
  u16*  qb      = (u16*)alloc((size_t)2 * 16 * Tn * 128 * 2);
  u16*  kb      = (u16*)alloc((size_t)2 * 4 * Tn * 128 * 2);
  u16*  vb      = (u16*)alloc((size_t)2 * 4 * Tn * 128 * 2);
  float* x1     = (float*)alloc((size_t)BTn * Cn * 4);  // residual stream (fp32)
  u16*  hbuf    = (u16*)alloc((size_t)BTn * HID * 2);   // gelu(fc) output (bf16)
  // total ~256 MB of ws

  dim3 tb(32, 8);
  transpose_f2b<<<dim3(NQKV / 32, Cn / 32), tb, 0, stream>>>(w_attn, wT_attn, Cn, NQKV);
  transpose_f2b<<<dim3(Cn / 32, Cn / 32), tb, 0, stream>>>(w_proj, wT_proj, Cn, Cn);
  transpose_f2b<<<dim3(HID / 32, Cn / 32), tb, 0, stream>>>(w_fc, wT_fc, Cn, HID);
  transpose_f2b<<<dim3(Cn / 32, HID / 32), tb, 0, stream>>>(w_mp, wT_mp, HID, Cn);

  layernorm_k<<<BTn, 256, 0, stream>>>(x, ln1w, ln1b, n12);
  gemm_bt<0><<<dim3(NQKV / 128, BTn / 128), 256, 0, stream>>>(n12, wT_attn, nullptr, qkv, nullptr, BTn, NQKV, Cn);
  rope_split<<<(int)(((long)BTn * NQKV) / 256), 256, 0, stream>>>(qkv, cosb, sinb, qb, kb, vb);
  attn_k<<<dim3(Tn, 32), 256, 0, stream>>>(qb, kb, vb, qkv /* y reuse */);
  gemm_bt<1><<<dim3(Cn / 128, BTn / 128), 256, 0, stream>>>(qkv, wT_proj, x, nullptr, x1, BTn, Cn, Cn);
  layernorm_k<<<BTn, 256, 0, stream>>>(x1, ln2w, ln2b, n12);
  gemm_bt<2><<<dim3(HID / 128, BTn / 128), 256, 0, stream>>>(n12, wT_fc, nullptr, hbuf, nullptr, BTn, HID, Cn);
  gemm_bt<1><<<dim3(Cn / 128, BTn / 128), 256, 0, stream>>>(hbuf, wT_mp, x1, nullptr, out, BTn, Cn, HID);
}

// Round 3
// 942.660 us; speedup vs baseline: 19.1095x; 19.1095x over previous
//
#include <hip/hip_runtime.h>
#include <stdint.h>
#include <math.h>

// Problem constants (B=2, T=2048, C=2048, NH=16, NG=4, HS=128)
#define Tn   2048
#define Cn   2048
#define BTn  4096          // B*T
#define NQKV 3072          // (16+2*4)*128
#define HID  8192

typedef unsigned short u16;
typedef float f32x4 __attribute__((ext_vector_type(4)));
typedef short s16x8 __attribute__((ext_vector_type(8)));   // 8 bf16 in 4 VGPRs

__device__ __forceinline__ float b2f(u16 u) { return __uint_as_float(((unsigned)u) << 16); }
__device__ __forceinline__ u16 f2b(float f) {
  unsigned i = __float_as_uint(f);
  return (u16)((i + 0x7fffu + ((i >> 16) & 1u)) >> 16);   // RNE
}

// async 16B global->LDS (lds dest is wave-uniform base; HW scatters lane*16)
__device__ __forceinline__ void g2l16(const void* g, void* l) {
  __builtin_amdgcn_global_load_lds((const __attribute__((address_space(1))) unsigned int*)g,
                                   (__attribute__((address_space(3))) unsigned int*)l,
                                   16, 0, 0);
}

// ------- tiled transpose + fp32->bf16 cast: out[c][r] = bf16(in[r][c]) -------
__global__ __launch_bounds__(256) void transpose_f2b(const float* __restrict__ in,
                                                     u16* __restrict__ out, int R, int C) {
  __shared__ float tile[32][33];
  int bx = blockIdx.x * 32, by = blockIdx.y * 32;
  int tx = threadIdx.x, ty = threadIdx.y;  // (32,8)
  #pragma unroll
  for (int j = 0; j < 32; j += 8)
    tile[ty + j][tx] = in[(size_t)(by + ty + j) * C + bx + tx];
  __syncthreads();
  #pragma unroll
  for (int j = 0; j < 32; j += 8)
    out[(size_t)(bx + ty + j) * R + by + tx] = f2b(tile[tx][ty + j]);
}

// ------- tiled u16 transpose with batch dim: out[z][c][r] = in[z][r][c] -------
__global__ __launch_bounds__(256) void transpose_u16(const u16* __restrict__ in,
                                                     u16* __restrict__ out, int R, int C) {
  __shared__ u16 tile[32][33];
  const size_t zb = (size_t)blockIdx.z * R * C;
  int bx = blockIdx.x * 32, by = blockIdx.y * 32;
  int tx = threadIdx.x, ty = threadIdx.y;  // (32,8)
  #pragma unroll
  for (int j = 0; j < 32; j += 8)
    tile[ty + j][tx] = in[zb + (size_t)(by + ty + j) * C + bx + tx];
  __syncthreads();
  #pragma unroll
  for (int j = 0; j < 32; j += 8)
    out[zb + (size_t)(bx + ty + j) * R + by + tx] = tile[tx][ty + j];
}

// ---------------- layernorm: fp32 in, bf16 out ----------------
__global__ __launch_bounds__(256)
void layernorm_k(const float* __restrict__ x, const float* __restrict__ w,
                 const float* __restrict__ bb, u16* __restrict__ out) {
  __shared__ float red[256];
  __shared__ float sm, sv;
  const int tid = threadIdx.x;
  const long row = blockIdx.x;
  const float* xr = x + row * (long)Cn;
  float v[8];
  float s = 0.f;
  #pragma unroll
  for (int i = 0; i < 8; ++i) { v[i] = xr[i * 256 + tid]; s += v[i]; }
  red[tid] = s; __syncthreads();
  for (int st = 128; st > 0; st >>= 1) { if (tid < st) red[tid] += red[tid + st]; __syncthreads(); }
  if (tid == 0) sm = red[0] * (1.f / Cn);
  __syncthreads();
  const float mean = sm;
  float s2 = 0.f;
  #pragma unroll
  for (int i = 0; i < 8; ++i) { float d = v[i] - mean; s2 += d * d; }
  red[tid] = s2; __syncthreads();
  for (int st = 128; st > 0; st >>= 1) { if (tid < st) red[tid] += red[tid + st]; __syncthreads(); }
  if (tid == 0) sv = rsqrtf(red[0] * (1.f / Cn) + 1e-5f);
  __syncthreads();
  const float rstd = sv;
  #pragma unroll
  for (int i = 0; i < 8; ++i) {
    int c = i * 256 + tid;
    out[row * (long)Cn + c] = f2b((v[i] - mean) * rstd * w[c] + bb[c]);
  }
}

// ---- RoPE + split qkv(bf16) -> q[b,h,t,d], k[b,g,t,d], v[b,g,t,d] (bf16) ----
__global__ __launch_bounds__(256)
void rope_split(const u16* __restrict__ qkv, const float* __restrict__ cs,
                const float* __restrict__ sn, u16* __restrict__ q,
                u16* __restrict__ k, u16* __restrict__ v) {
  const long idx = (long)blockIdx.x * 256 + threadIdx.x;
  const int row = (int)(idx / NQKV);       // b*T + t
  const int col = (int)(idx % NQKV);
  const int b = row >> 11, t = row & 2047;
  const int g = col / 768, rr = col % 768, s = rr >> 7, d = rr & 127;
  const u16 raw = qkv[idx];
  if (s == 5) { v[((long)(b * 4 + g) * Tn + t) * 128 + d] = raw; return; }
  const float xv = b2f(raw);
  const float x2 = b2f(qkv[idx - d + (d ^ 64)]);
  const float c = cs[t * 128 + d];
  const float si = sn[t * 128 + d];
  const float rot = (d < 64) ? -x2 : x2;
  const float o = xv * c + rot * si;
  if (s == 4) k[((long)(b * 4 + g) * Tn + t) * 128 + d] = f2b(o);
  else        q[((long)(b * 16 + g * 4 + s) * Tn + t) * 128 + d] = f2b(o);
}

// ------------- MFMA flash attention (causal GQA), bf16 I/O -------------
// Grid (T/64, B*NH). 4 waves; wave w owns Q rows bx*64+w*16 .. +15.
// K staged as 4 k-panels [64 t][32 k]; V^T staged as 2 t-panels [128 d][32 t].
// P (16x64 per wave) round-trips LDS in 2 panels [16][32] for A-frag reads.
__global__ __launch_bounds__(256, 2)
void attn_flash(const u16* __restrict__ q, const u16* __restrict__ k,
                const u16* __restrict__ vt, u16* __restrict__ y) {
  __shared__ __align__(16) u16 Ks[4 * 64 * 32];     // 16 KB
  __shared__ __align__(16) u16 Vs[2 * 128 * 32];    // 16 KB
  __shared__ __align__(16) u16 Ps[4][2 * 16 * 32];  // 8 KB (per-wave)
  const int tid = threadIdx.x, wave = tid >> 6, lane = tid & 63;
  const int fr = lane & 15, quad = lane >> 4;
  const int lr4 = lane >> 2, lc8 = (lane & 3) << 3;
  const int bx = blockIdx.x, bh = blockIdx.y;
  const int b = bh >> 4, h = bh & 15, g = h >> 2;
  const int bg = b * 4 + g;
  const u16* kg = k + (size_t)bg * Tn * 128;
  const u16* vg = vt + (size_t)bg * 128 * Tn;
  const int q0 = bx * 64 + wave * 16;

  // Q fragments in registers: A[m=fr][k=kc*32+quad*8+j]
  s16x8 qf[4];
  {
    const u16* qrow = q + ((size_t)bh * Tn + q0 + fr) * 128;
    #pragma unroll
    for (int kc = 0; kc < 4; ++kc)
      qf[kc] = *(const s16x8*)(qrow + kc * 32 + quad * 8);
  }
  f32x4 o_acc[8] = {};                 // O[16][128], C-layout per 16-col tile
  float m_r[4], l_r[4];
  #pragma unroll
  for (int r = 0; r < 4; ++r) { m_r[r] = -1e30f; l_r[r] = 0.f; }
  const float scale = 0.08838834764831845f;  // 1/sqrt(128)

  for (int step = 0; step <= bx; ++step) {
    const int j0 = step * 64;
    __syncthreads();                   // prior iter's LDS reads done
    // stage K tile: wave w -> rows w*16..+15, all 4 k-panels
    #pragma unroll
    for (int kc = 0; kc < 4; ++kc)
      g2l16(kg + (size_t)(j0 + wave * 16 + lr4) * 128 + kc * 32 + lc8,
            Ks + kc * 2048 + wave * 16 * 32);
    // stage V^T tile: wave w -> d-rows w*32..+31, both t-panels
    #pragma unroll
    for (int kc = 0; kc < 2; ++kc)
      #pragma unroll
      for (int hh = 0; hh < 2; ++hh)
        g2l16(vg + (size_t)(wave * 32 + hh * 16 + lr4) * Tn + j0 + kc * 32 + lc8,
              Vs + kc * 4096 + (wave * 32 + hh * 16) * 32);
    __syncthreads();                   // vmcnt(0) drain by compiler

    // S = Q * K^T  (16x64 per wave)
    f32x4 s[4] = {};
    #pragma unroll
    for (int kc = 0; kc < 4; ++kc)
      #pragma unroll
      for (int nt = 0; nt < 4; ++nt) {
        s16x8 bf = *(const s16x8*)(Ks + kc * 2048 + (nt * 16 + fr) * 32 + quad * 8);
        s[nt] = __builtin_amdgcn_mfma_f32_16x16x32_bf16(qf[kc], bf, s[nt], 0, 0, 0);
      }

    // online softmax; rows = q0 + quad*4 + r, cols = j0 + nt*16 + fr
    const bool diag = (step == bx);
    #pragma unroll
    for (int r = 0; r < 4; ++r) {
      float vmax = -1e30f;
      #pragma unroll
      for (int nt = 0; nt < 4; ++nt) {
        float sv = s[nt][r] * scale;
        if (diag && (j0 + nt * 16 + fr) > (q0 + quad * 4 + r)) sv = -1e30f;
        s[nt][r] = sv;
        vmax = fmaxf(vmax, sv);
      }
      #pragma unroll
      for (int mk = 1; mk < 16; mk <<= 1) vmax = fmaxf(vmax, __shfl_xor(vmax, mk, 64));
      const float mnew = fmaxf(m_r[r], vmax);
      const float alpha = __expf(m_r[r] - mnew);
      float rsum = 0.f;
      #pragma unroll
      for (int nt = 0; nt < 4; ++nt) {
        float pv = __expf(s[nt][r] - mnew);
        s[nt][r] = pv; rsum += pv;
      }
      #pragma unroll
      for (int mk = 1; mk < 16; mk <<= 1) rsum += __shfl_xor(rsum, mk, 64);
      l_r[r] = l_r[r] * alpha + rsum;
      m_r[r] = mnew;
      #pragma unroll
      for (int nt = 0; nt < 8; ++nt) o_acc[nt][r] *= alpha;
    }

    // P (C-layout) -> LDS panels (bf16), then A-frag reads
    u16* pw = Ps[wave];
    #pragma unroll
    for (int nt = 0; nt < 4; ++nt) {
      const int col = nt * 16 + fr, pan = col >> 5, cc = col & 31;
      #pragma unroll
      for (int r = 0; r < 4; ++r)
        pw[pan * 512 + (quad * 4 + r) * 32 + cc] = f2b(s[nt][r]);
    }
    // O += P * V  (k = t-dim, 2 panels of 32)
    #pragma unroll
    for (int kc = 0; kc < 2; ++kc) {
      s16x8 af = *(const s16x8*)(pw + kc * 512 + fr * 32 + quad * 8);
      #pragma unroll
      for (int nt = 0; nt < 8; ++nt) {
        s16x8 bf = *(const s16x8*)(Vs + kc * 4096 + (nt * 16 + fr) * 32 + quad * 8);
        o_acc[nt] = __builtin_amdgcn_mfma_f32_16x16x32_bf16(af, bf, o_acc[nt], 0, 0, 0);
      }
    }
  }

  // epilogue: y[b, t, h*128 + d] = O / l
  #pragma unroll
  for (int r = 0; r < 4; ++r) {
    const float inv = 1.f / l_r[r];
    const size_t row = (size_t)(b * Tn + q0 + quad * 4 + r) * Cn + h * 128;
    #pragma unroll
    for (int nt = 0; nt < 8; ++nt)
      y[row + nt * 16 + fr] = f2b(o_acc[nt][r] * inv);
  }
}

// ---------------- m97-style MFMA GEMM: C = A[MxK] * Bt[NxK]^T, fused epilogues ----------------
// EPI 0: ob (bf16)  = acc
// EPI 1: of (fp32)  = acc + res (fp32)     [residual add]
// EPI 2: ob (bf16)  = gelu_exact(acc)
template <int EPI>
__global__ __launch_bounds__(256, 2)
void gemm_bt(const u16* __restrict__ A, const u16* __restrict__ Bt,
             const float* __restrict__ res, u16* __restrict__ ob,
             float* __restrict__ of, int M, int N, int K) {
  __shared__ __align__(16) u16 As[128 * 32];
  __shared__ __align__(16) u16 Bs[128 * 32];
  const int tid = threadIdx.x;
  const int wave = tid >> 6, lane = tid & 63;
  const int wy = wave >> 1, wx = wave & 1;
  const long m0 = (long)blockIdx.y * 128, n0 = (long)blockIdx.x * 128;
  const int lr = lane >> 2;          // 0..15: row within 16-row segment
  const int lc = (lane & 3) << 3;    // 0,8,16,24: k-offset (u16 units)
  const int fr = lane & 15, quad = lane >> 4;
  f32x4 acc[4][4] = {};

  for (int k0 = 0; k0 < K; k0 += 32) {
    __syncthreads();
    #pragma unroll
    for (int i = 0; i < 2; ++i) {
      const int seg = wave * 2 + i;          // 0..7, wave-uniform
      const int row = seg * 16 + lr;         // 0..127
      g2l16(A + (m0 + row) * (long)K + k0 + lc, As + seg * 512);
      g2l16(Bt + (n0 + row) * (long)K + k0 + lc, Bs + seg * 512);
    }
    __syncthreads();   // compiler emits vmcnt(0) drain before barrier
    s16x8 af[4], bfr[4];
    #pragma unroll
    for (int mi = 0; mi < 4; ++mi)
      af[mi] = *(const s16x8*)(As + (wy * 64 + mi * 16 + fr) * 32 + quad * 8);
    #pragma unroll
    for (int ni = 0; ni < 4; ++ni)
      bfr[ni] = *(const s16x8*)(Bs + (wx * 64 + ni * 16 + fr) * 32 + quad * 8);
    #pragma unroll
    for (int mi = 0; mi < 4; ++mi)
      #pragma unroll
      for (int ni = 0; ni < 4; ++ni)
        acc[mi][ni] = __builtin_amdgcn_mfma_f32_16x16x32_bf16(af[mi], bfr[ni], acc[mi][ni], 0, 0, 0);
  }

  #pragma unroll
  for (int mi = 0; mi < 4; ++mi)
    #pragma unroll
    for (int ni = 0; ni < 4; ++ni)
      #pragma unroll
      for (int r = 0; r < 4; ++r) {
        const long row = m0 + wy * 64 + mi * 16 + quad * 4 + r;
        const long col = n0 + wx * 64 + ni * 16 + fr;
        const long idx = row * N + col;
        const float vv = acc[mi][ni][r];
        if (EPI == 0) ob[idx] = f2b(vv);
        else if (EPI == 1) of[idx] = vv + res[idx];
        else ob[idx] = f2b(0.5f * vv * (1.0f + erff(vv * 0.70710678118654752f)));
      }
}

extern "C" void kernel_launch(void* const* d_in, const int* in_sizes, int n_in,
                              void* d_out, int out_size, void* d_ws, size_t ws_size,
                              hipStream_t stream) {
  (void)in_sizes; (void)n_in; (void)out_size; (void)ws_size;
  const float* x      = (const float*)d_in[0];
  const float* cosb   = (const float*)d_in[1];
  const float* sinb   = (const float*)d_in[2];
  const float* ln1w   = (const float*)d_in[3];
  const float* ln1b   = (const float*)d_in[4];
  const float* ln2w   = (const float*)d_in[5];
  const float* ln2b   = (const float*)d_in[6];
  const float* w_attn = (const float*)d_in[7];
  const float* w_proj = (const float*)d_in[8];
  const float* w_fc   = (const float*)d_in[9];
  const float* w_mp   = (const float*)d_in[10];
  float* out = (float*)d_out;

  char* p = (char*)d_ws;
  auto alloc = [&](size_t bytes) { char* r = p; p += (bytes + 255) & ~(size_t)255; return (void*)r; };
  u16*  wT_attn = (u16*)alloc((size_t)NQKV * Cn * 2);   // bf16 [3072][2048]
  u16*  wT_proj = (u16*)alloc((size_t)Cn * Cn * 2);     // bf16 [2048][2048]
  u16*  wT_fc   = (u16*)alloc((size_t)HID * Cn * 2);    // bf16 [8192][2048]
  u16*  wT_mp   = (u16*)alloc((size_t)Cn * HID * 2);    // bf16 [2048][8192]
  u16*  n12     = (u16*)alloc((size_t)BTn * Cn * 2);    // n1 / vt(attn phase) / n2
  u16*  qkv     = (u16*)alloc((size_t)BTn * NQKV * 2);  // qkv, then y (bf16)
  u16*  qb      = (u16*)alloc((size_t)2 * 16 * Tn * 128 * 2);
  u16*  kb      = (u16*)alloc((size_t)2 * 4 * Tn * 128 * 2);
  u16*  vb      = (u16*)alloc((size_t)2 * 4 * Tn * 128 * 2);
  float* x1     = (float*)alloc((size_t)BTn * Cn * 4);  // residual stream (fp32)
  u16*  hbuf    = (u16*)alloc((size_t)BTn * HID * 2);   // gelu(fc) output (bf16)
  // n12 (16.8 MB) is idle between gemm<0> and layernorm#2 -> reuse as vt (4.2 MB)
  u16*  vt      = n12;                                  // [b,g,d,t] transposed V

  dim3 tb(32, 8);
  transpose_f2b<<<dim3(NQKV / 32, Cn / 32), tb, 0, stream>>>(w_attn, wT_attn, Cn, NQKV);
  transpose_f2b<<<dim3(Cn / 32, Cn / 32), tb, 0, stream>>>(w_proj, wT_proj, Cn, Cn);
  transpose_f2b<<<dim3(HID / 32, Cn / 32), tb, 0, stream>>>(w_fc, wT_fc, Cn, HID);
  transpose_f2b<<<dim3(Cn / 32, HID / 32), tb, 0, stream>>>(w_mp, wT_mp, HID, Cn);

  layernorm_k<<<BTn, 256, 0, stream>>>(x, ln1w, ln1b, n12);
  gemm_bt<0><<<dim3(NQKV / 128, BTn / 128), 256, 0, stream>>>(n12, wT_attn, nullptr, qkv, nullptr, BTn, NQKV, Cn);
  rope_split<<<(int)(((long)BTn * NQKV) / 256), 256, 0, stream>>>(qkv, cosb, sinb, qb, kb, vb);
  // v[b,g,t,d] -> vt[b,g,d,t]  (overwrites n12 region, which is free here)
  transpose_u16<<<dim3(128 / 32, Tn / 32, 8), tb, 0, stream>>>(vb, vt, Tn, 128);
  attn_flash<<<dim3(Tn / 64, 32), 256, 0, stream>>>(qb, kb, vt, qkv /* y reuse */);
  gemm_bt<1><<<dim3(Cn / 128, BTn / 128), 256, 0, stream>>>(qkv, wT_proj, x, nullptr, x1, BTn, Cn, Cn);
  layernorm_k<<<BTn, 256, 0, stream>>>(x1, ln2w, ln2b, n12);
  gemm_bt<2><<<dim3(HID / 128, BTn / 128), 256, 0, stream>>>(n12, wT_fc, nullptr, hbuf, nullptr, BTn, HID, Cn);
  gemm_bt<1><<<dim3(Cn / 128, BTn / 128), 256, 0, stream>>>(hbuf, wT_mp, x1, nullptr, out, BTn, Cn, HID);
}

// Round 4
// 916.820 us; speedup vs baseline: 19.6481x; 1.0282x over previous
//
#include <hip/hip_runtime.h>
#include <stdint.h>
#include <math.h>

// Problem constants (B=2, T=2048, C=2048, NH=16, NG=4, HS=128)
#define Tn   2048
#define Cn   2048
#define BTn  4096          // B*T
#define NQKV 3072          // (16+2*4)*128
#define HID  8192

typedef unsigned short u16;
typedef float f32x4 __attribute__((ext_vector_type(4)));
typedef short s16x8 __attribute__((ext_vector_type(8)));   // 8 bf16 in 4 VGPRs

__device__ __forceinline__ float b2f(u16 u) { return __uint_as_float(((unsigned)u) << 16); }
__device__ __forceinline__ u16 f2b(float f) {
  unsigned i = __float_as_uint(f);
  return (u16)((i + 0x7fffu + ((i >> 16) & 1u)) >> 16);   // RNE
}

// async 16B global->LDS (lds dest is wave-uniform base; HW scatters lane*16)
__device__ __forceinline__ void g2l16(const void* g, void* l) {
  __builtin_amdgcn_global_load_lds((const __attribute__((address_space(1))) unsigned int*)g,
                                   (__attribute__((address_space(3))) unsigned int*)l,
                                   16, 0, 0);
}

// ------- tiled transpose + fp32->bf16 cast: out[c][r] = bf16(in[r][c]) -------
__global__ __launch_bounds__(256) void transpose_f2b(const float* __restrict__ in,
                                                     u16* __restrict__ out, int R, int C) {
  __shared__ float tile[32][33];
  int bx = blockIdx.x * 32, by = blockIdx.y * 32;
  int tx = threadIdx.x, ty = threadIdx.y;  // (32,8)
  #pragma unroll
  for (int j = 0; j < 32; j += 8)
    tile[ty + j][tx] = in[(size_t)(by + ty + j) * C + bx + tx];
  __syncthreads();
  #pragma unroll
  for (int j = 0; j < 32; j += 8)
    out[(size_t)(bx + ty + j) * R + by + tx] = f2b(tile[tx][ty + j]);
}

// ------- tiled u16 transpose with batch dim: out[z][c][r] = in[z][r][c] -------
__global__ __launch_bounds__(256) void transpose_u16(const u16* __restrict__ in,
                                                     u16* __restrict__ out, int R, int C) {
  __shared__ u16 tile[32][33];
  const size_t zb = (size_t)blockIdx.z * R * C;
  int bx = blockIdx.x * 32, by = blockIdx.y * 32;
  int tx = threadIdx.x, ty = threadIdx.y;  // (32,8)
  #pragma unroll
  for (int j = 0; j < 32; j += 8)
    tile[ty + j][tx] = in[zb + (size_t)(by + ty + j) * C + bx + tx];
  __syncthreads();
  #pragma unroll
  for (int j = 0; j < 32; j += 8)
    out[zb + (size_t)(bx + ty + j) * R + by + tx] = tile[tx][ty + j];
}

// ---------------- layernorm: fp32 in, bf16 out ----------------
__global__ __launch_bounds__(256)
void layernorm_k(const float* __restrict__ x, const float* __restrict__ w,
                 const float* __restrict__ bb, u16* __restrict__ out) {
  __shared__ float red[256];
  __shared__ float sm, sv;
  const int tid = threadIdx.x;
  const long row = blockIdx.x;
  const float* xr = x + row * (long)Cn;
  float v[8];
  float s = 0.f;
  #pragma unroll
  for (int i = 0; i < 8; ++i) { v[i] = xr[i * 256 + tid]; s += v[i]; }
  red[tid] = s; __syncthreads();
  for (int st = 128; st > 0; st >>= 1) { if (tid < st) red[tid] += red[tid + st]; __syncthreads(); }
  if (tid == 0) sm = red[0] * (1.f / Cn);
  __syncthreads();
  const float mean = sm;
  float s2 = 0.f;
  #pragma unroll
  for (int i = 0; i < 8; ++i) { float d = v[i] - mean; s2 += d * d; }
  red[tid] = s2; __syncthreads();
  for (int st = 128; st > 0; st >>= 1) { if (tid < st) red[tid] += red[tid + st]; __syncthreads(); }
  if (tid == 0) sv = rsqrtf(red[0] * (1.f / Cn) + 1e-5f);
  __syncthreads();
  const float rstd = sv;
  #pragma unroll
  for (int i = 0; i < 8; ++i) {
    int c = i * 256 + tid;
    out[row * (long)Cn + c] = f2b((v[i] - mean) * rstd * w[c] + bb[c]);
  }
}

// ---- RoPE + split qkv(bf16) -> q[b,h,t,d], k[b,g,t,d], v[b,g,t,d] (bf16) ----
__global__ __launch_bounds__(256)
void rope_split(const u16* __restrict__ qkv, const float* __restrict__ cs,
                const float* __restrict__ sn, u16* __restrict__ q,
                u16* __restrict__ k, u16* __restrict__ v) {
  const long idx = (long)blockIdx.x * 256 + threadIdx.x;
  const int row = (int)(idx / NQKV);       // b*T + t
  const int col = (int)(idx % NQKV);
  const int b = row >> 11, t = row & 2047;
  const int g = col / 768, rr = col % 768, s = rr >> 7, d = rr & 127;
  const u16 raw = qkv[idx];
  if (s == 5) { v[((long)(b * 4 + g) * Tn + t) * 128 + d] = raw; return; }
  const float xv = b2f(raw);
  const float x2 = b2f(qkv[idx - d + (d ^ 64)]);
  const float c = cs[t * 128 + d];
  const float si = sn[t * 128 + d];
  const float rot = (d < 64) ? -x2 : x2;
  const float o = xv * c + rot * si;
  if (s == 4) k[((long)(b * 4 + g) * Tn + t) * 128 + d] = f2b(o);
  else        q[((long)(b * 16 + g * 4 + s) * Tn + t) * 128 + d] = f2b(o);
}

// ------------- MFMA flash attention (causal GQA), bf16 I/O -------------
// Grid (T/64, B*NH). 4 waves; wave w owns Q rows bx*64+w*16 .. +15.
__global__ __launch_bounds__(256, 2)
void attn_flash(const u16* __restrict__ q, const u16* __restrict__ k,
                const u16* __restrict__ vt, u16* __restrict__ y) {
  __shared__ __align__(16) u16 Ks[4 * 64 * 32];     // 16 KB
  __shared__ __align__(16) u16 Vs[2 * 128 * 32];    // 16 KB
  __shared__ __align__(16) u16 Ps[4][2 * 16 * 32];  // 8 KB (per-wave)
  const int tid = threadIdx.x, wave = tid >> 6, lane = tid & 63;
  const int fr = lane & 15, quad = lane >> 4;
  const int lr4 = lane >> 2, lc8 = (lane & 3) << 3;
  const int bx = blockIdx.x, bh = blockIdx.y;
  const int b = bh >> 4, h = bh & 15, g = h >> 2;
  const int bg = b * 4 + g;
  const u16* kg = k + (size_t)bg * Tn * 128;
  const u16* vg = vt + (size_t)bg * 128 * Tn;
  const int q0 = bx * 64 + wave * 16;

  // Q fragments in registers: A[m=fr][k=kc*32+quad*8+j]
  s16x8 qf[4];
  {
    const u16* qrow = q + ((size_t)bh * Tn + q0 + fr) * 128;
    #pragma unroll
    for (int kc = 0; kc < 4; ++kc)
      qf[kc] = *(const s16x8*)(qrow + kc * 32 + quad * 8);
  }
  f32x4 o_acc[8] = {};                 // O[16][128], C-layout per 16-col tile
  float m_r[4], l_r[4];
  #pragma unroll
  for (int r = 0; r < 4; ++r) { m_r[r] = -1e30f; l_r[r] = 0.f; }
  const float scale = 0.08838834764831845f;  // 1/sqrt(128)

  for (int step = 0; step <= bx; ++step) {
    const int j0 = step * 64;
    __syncthreads();                   // prior iter's LDS reads done
    #pragma unroll
    for (int kc = 0; kc < 4; ++kc)
      g2l16(kg + (size_t)(j0 + wave * 16 + lr4) * 128 + kc * 32 + lc8,
            Ks + kc * 2048 + wave * 16 * 32);
    #pragma unroll
    for (int kc = 0; kc < 2; ++kc)
      #pragma unroll
      for (int hh = 0; hh < 2; ++hh)
        g2l16(vg + (size_t)(wave * 32 + hh * 16 + lr4) * Tn + j0 + kc * 32 + lc8,
              Vs + kc * 4096 + (wave * 32 + hh * 16) * 32);
    __syncthreads();                   // vmcnt(0) drain by compiler

    // S = Q * K^T  (16x64 per wave)
    f32x4 s[4] = {};
    #pragma unroll
    for (int kc = 0; kc < 4; ++kc)
      #pragma unroll
      for (int nt = 0; nt < 4; ++nt) {
        s16x8 bf = *(const s16x8*)(Ks + kc * 2048 + (nt * 16 + fr) * 32 + quad * 8);
        s[nt] = __builtin_amdgcn_mfma_f32_16x16x32_bf16(qf[kc], bf, s[nt], 0, 0, 0);
      }

    // online softmax; rows = q0 + quad*4 + r, cols = j0 + nt*16 + fr
    const bool diag = (step == bx);
    #pragma unroll
    for (int r = 0; r < 4; ++r) {
      float vmax = -1e30f;
      #pragma unroll
      for (int nt = 0; nt < 4; ++nt) {
        float sv = s[nt][r] * scale;
        if (diag && (j0 + nt * 16 + fr) > (q0 + quad * 4 + r)) sv = -1e30f;
        s[nt][r] = sv;
        vmax = fmaxf(vmax, sv);
      }
      #pragma unroll
      for (int mk = 1; mk < 16; mk <<= 1) vmax = fmaxf(vmax, __shfl_xor(vmax, mk, 64));
      const float mnew = fmaxf(m_r[r], vmax);
      const float alpha = __expf(m_r[r] - mnew);
      float rsum = 0.f;
      #pragma unroll
      for (int nt = 0; nt < 4; ++nt) {
        float pv = __expf(s[nt][r] - mnew);
        s[nt][r] = pv; rsum += pv;
      }
      #pragma unroll
      for (int mk = 1; mk < 16; mk <<= 1) rsum += __shfl_xor(rsum, mk, 64);
      l_r[r] = l_r[r] * alpha + rsum;
      m_r[r] = mnew;
      #pragma unroll
      for (int nt = 0; nt < 8; ++nt) o_acc[nt][r] *= alpha;
    }

    // P (C-layout) -> LDS panels (bf16), then A-frag reads
    u16* pw = Ps[wave];
    #pragma unroll
    for (int nt = 0; nt < 4; ++nt) {
      const int col = nt * 16 + fr, pan = col >> 5, cc = col & 31;
      #pragma unroll
      for (int r = 0; r < 4; ++r)
        pw[pan * 512 + (quad * 4 + r) * 32 + cc] = f2b(s[nt][r]);
    }
    // O += P * V  (k = t-dim, 2 panels of 32)
    #pragma unroll
    for (int kc = 0; kc < 2; ++kc) {
      s16x8 af = *(const s16x8*)(pw + kc * 512 + fr * 32 + quad * 8);
      #pragma unroll
      for (int nt = 0; nt < 8; ++nt) {
        s16x8 bf = *(const s16x8*)(Vs + kc * 4096 + (nt * 16 + fr) * 32 + quad * 8);
        o_acc[nt] = __builtin_amdgcn_mfma_f32_16x16x32_bf16(af, bf, o_acc[nt], 0, 0, 0);
      }
    }
  }

  // epilogue: y[b, t, h*128 + d] = O / l
  #pragma unroll
  for (int r = 0; r < 4; ++r) {
    const float inv = 1.f / l_r[r];
    const size_t row = (size_t)(b * Tn + q0 + quad * 4 + r) * Cn + h * 128;
    #pragma unroll
    for (int nt = 0; nt < 8; ++nt)
      y[row + nt * 16 + fr] = f2b(o_acc[nt][r] * inv);
  }
}

// ---------------- m97-style MFMA GEMM, XCD-aware 4x4 patch swizzle ----------------
// 1-D grid of num_m*num_n blocks. xcd = pid&7; each XCD owns whole 4x4 tile
// patches (16 blocks consecutive in pid/8) -> A/B panels reused 4x from its L2.
// Requires num_m%4==0, num_n%4==0, (num_m/4)*(num_n/4)%8==0 (all shapes here ok).
// EPI 0: ob (bf16) = acc ; EPI 1: of (fp32) = acc + res ; EPI 2: ob = gelu(acc)
template <int EPI>
__global__ __launch_bounds__(256, 2)
void gemm_bt(const u16* __restrict__ A, const u16* __restrict__ Bt,
             const float* __restrict__ res, u16* __restrict__ ob,
             float* __restrict__ of, int M, int N, int K, int num_n) {
  __shared__ __align__(16) u16 As[128 * 32];
  __shared__ __align__(16) u16 Bs[128 * 32];
  const int pid = blockIdx.x;
  const int xcd = pid & 7, idx = pid >> 3;
  const int j = idx & 15;              // position within 4x4 patch
  const int gp = (idx >> 4) * 8 + xcd; // global patch id
  const int npc = num_n >> 2;          // patches per m-row of patches
  const int pr = gp / npc, pc = gp - pr * npc;
  const long m0 = (long)(pr * 4 + (j & 3)) * 128;
  const long n0 = (long)(pc * 4 + (j >> 2)) * 128;

  const int tid = threadIdx.x;
  const int wave = tid >> 6, lane = tid & 63;
  const int wy = wave >> 1, wx = wave & 1;
  const int lr = lane >> 2;          // 0..15: row within 16-row segment
  const int lc = (lane & 3) << 3;    // 0,8,16,24: k-offset (u16 units)
  const int fr = lane & 15, quad = lane >> 4;
  f32x4 acc[4][4] = {};

  for (int k0 = 0; k0 < K; k0 += 32) {
    __syncthreads();
    #pragma unroll
    for (int i = 0; i < 2; ++i) {
      const int seg = wave * 2 + i;          // 0..7, wave-uniform
      const int row = seg * 16 + lr;         // 0..127
      g2l16(A + (m0 + row) * (long)K + k0 + lc, As + seg * 512);
      g2l16(Bt + (n0 + row) * (long)K + k0 + lc, Bs + seg * 512);
    }
    __syncthreads();   // compiler emits vmcnt(0) drain before barrier
    s16x8 af[4], bfr[4];
    #pragma unroll
    for (int mi = 0; mi < 4; ++mi)
      af[mi] = *(const s16x8*)(As + (wy * 64 + mi * 16 + fr) * 32 + quad * 8);
    #pragma unroll
    for (int ni = 0; ni < 4; ++ni)
      bfr[ni] = *(const s16x8*)(Bs + (wx * 64 + ni * 16 + fr) * 32 + quad * 8);
    #pragma unroll
    for (int mi = 0; mi < 4; ++mi)
      #pragma unroll
      for (int ni = 0; ni < 4; ++ni)
        acc[mi][ni] = __builtin_amdgcn_mfma_f32_16x16x32_bf16(af[mi], bfr[ni], acc[mi][ni], 0, 0, 0);
  }

  #pragma unroll
  for (int mi = 0; mi < 4; ++mi)
    #pragma unroll
    for (int ni = 0; ni < 4; ++ni)
      #pragma unroll
      for (int r = 0; r < 4; ++r) {
        const long row = m0 + wy * 64 + mi * 16 + quad * 4 + r;
        const long col = n0 + wx * 64 + ni * 16 + fr;
        const long idx2 = row * N + col;
        const float vv = acc[mi][ni][r];
        if (EPI == 0) ob[idx2] = f2b(vv);
        else if (EPI == 1) of[idx2] = vv + res[idx2];
        else ob[idx2] = f2b(0.5f * vv * (1.0f + erff(vv * 0.70710678118654752f)));
      }
}

extern "C" void kernel_launch(void* const* d_in, const int* in_sizes, int n_in,
                              void* d_out, int out_size, void* d_ws, size_t ws_size,
                              hipStream_t stream) {
  (void)in_sizes; (void)n_in; (void)out_size; (void)ws_size;
  const float* x      = (const float*)d_in[0];
  const float* cosb   = (const float*)d_in[1];
  const float* sinb   = (const float*)d_in[2];
  const float* ln1w   = (const float*)d_in[3];
  const float* ln1b   = (const float*)d_in[4];
  const float* ln2w   = (const float*)d_in[5];
  const float* ln2b   = (const float*)d_in[6];
  const float* w_attn = (const float*)d_in[7];
  const float* w_proj = (const float*)d_in[8];
  const float* w_fc   = (const float*)d_in[9];
  const float* w_mp   = (const float*)d_in[10];
  float* out = (float*)d_out;

  char* p = (char*)d_ws;
  auto alloc = [&](size_t bytes) { char* r = p; p += (bytes + 255) & ~(size_t)255; return (void*)r; };
  u16*  wT_attn = (u16*)alloc((size_t)NQKV * Cn * 2);   // bf16 [3072][2048]
  u16*  wT_proj = (u16*)alloc((size_t)Cn * Cn * 2);     // bf16 [2048][2048]
  u16*  wT_fc   = (u16*)alloc((size_t)HID * Cn * 2);    // bf16 [8192][2048]
  u16*  wT_mp   = (u16*)alloc((size_t)Cn * HID * 2);    // bf16 [2048][8192]
  u16*  n12     = (u16*)alloc((size_t)BTn * Cn * 2);    // n1 / vt(attn phase) / n2
  u16*  qkv     = (u16*)alloc((size_t)BTn * NQKV * 2);  // qkv, then y (bf16)
  u16*  qb      = (u16*)alloc((size_t)2 * 16 * Tn * 128 * 2);
  u16*  kb      = (u16*)alloc((size_t)2 * 4 * Tn * 128 * 2);
  u16*  vb      = (u16*)alloc((size_t)2 * 4 * Tn * 128 * 2);
  float* x1     = (float*)alloc((size_t)BTn * Cn * 4);  // residual stream (fp32)
  u16*  hbuf    = (u16*)alloc((size_t)BTn * HID * 2);   // gelu(fc) output (bf16)
  u16*  vt      = n12;                                  // [b,g,d,t] transposed V

  dim3 tb(32, 8);
  transpose_f2b<<<dim3(NQKV / 32, Cn / 32), tb, 0, stream>>>(w_attn, wT_attn, Cn, NQKV);
  transpose_f2b<<<dim3(Cn / 32, Cn / 32), tb, 0, stream>>>(w_proj, wT_proj, Cn, Cn);
  transpose_f2b<<<dim3(HID / 32, Cn / 32), tb, 0, stream>>>(w_fc, wT_fc, Cn, HID);
  transpose_f2b<<<dim3(Cn / 32, HID / 32), tb, 0, stream>>>(w_mp, wT_mp, HID, Cn);

  layernorm_k<<<BTn, 256, 0, stream>>>(x, ln1w, ln1b, n12);
  gemm_bt<0><<<(BTn / 128) * (NQKV / 128), 256, 0, stream>>>(n12, wT_attn, nullptr, qkv, nullptr, BTn, NQKV, Cn, NQKV / 128);
  rope_split<<<(int)(((long)BTn * NQKV) / 256), 256, 0, stream>>>(qkv, cosb, sinb, qb, kb, vb);
  transpose_u16<<<dim3(128 / 32, Tn / 32, 8), tb, 0, stream>>>(vb, vt, Tn, 128);
  attn_flash<<<dim3(Tn / 64, 32), 256, 0, stream>>>(qb, kb, vt, qkv /* y reuse */);
  gemm_bt<1><<<(BTn / 128) * (Cn / 128), 256, 0, stream>>>(qkv, wT_proj, x, nullptr, x1, BTn, Cn, Cn, Cn / 128);
  layernorm_k<<<BTn, 256, 0, stream>>>(x1, ln2w, ln2b, n12);
  gemm_bt<2><<<(BTn / 128) * (HID / 128), 256, 0, stream>>>(n12, wT_fc, nullptr, hbuf, nullptr, BTn, HID, Cn, HID / 128);
  gemm_bt<1><<<(BTn / 128) * (Cn / 128), 256, 0, stream>>>(hbuf, wT_mp, x1, nullptr, out, BTn, Cn, HID, Cn / 128);
}